// Round 7
// baseline (705.202 us; speedup 1.0000x reference)
//
#include <hip/hip_runtime.h>
#include <stdint.h>

#define QLEN 1024
#define KLEN 2048
#define BSZ  4
#define NH   16
#define HD   64
#define EMB  1024
#define PREVL 1024
#define SLOG2E 0.045084220027780106f   // (1/32) * log2(e): fold softmax scale + exp2 conversion

typedef __attribute__((ext_vector_type(4))) float f32x4;
typedef __attribute__((ext_vector_type(8))) short bf16x8;
typedef __attribute__((ext_vector_type(4))) short bf16x4;

__device__ __forceinline__ unsigned short f2bf(float f){
  unsigned u = __float_as_uint(f);
  u += 0x7fffu + ((u >> 16) & 1u);
  return (unsigned short)(u >> 16);
}

__device__ __forceinline__ void gload_lds16(const void* g, void* l){
  __builtin_amdgcn_global_load_lds((const __attribute__((address_space(1))) void*)g,
                                   (__attribute__((address_space(3))) void*)l, 16, 0, 0);
}

// ---------------- fused 5x W transpose: f32 [k][n] -> bf16 [n][k] ----------------
__global__ void txl_transpose5(const float* __restrict__ w0, const float* __restrict__ w1,
                               const float* __restrict__ w2, const float* __restrict__ w3,
                               const float* __restrict__ w4,
                               unsigned short* __restrict__ o0, unsigned short* __restrict__ o1,
                               unsigned short* __restrict__ o2, unsigned short* __restrict__ o3,
                               unsigned short* __restrict__ o4){
  const float* in; unsigned short* out;
  switch (blockIdx.z){
    case 0: in = w0; out = o0; break;
    case 1: in = w1; out = o1; break;
    case 2: in = w2; out = o2; break;
    case 3: in = w3; out = o3; break;
    default: in = w4; out = o4; break;
  }
  __shared__ float tile[32][33];
  int tx = threadIdx.x, ty = threadIdx.y;
  int k0 = blockIdx.y * 32, n0 = blockIdx.x * 32;
  #pragma unroll
  for (int j = 0; j < 32; j += 8)
    tile[ty + j][tx] = in[(size_t)(k0 + ty + j) * EMB + n0 + tx];
  __syncthreads();
  #pragma unroll
  for (int j = 0; j < 32; j += 8)
    out[(size_t)(n0 + ty + j) * EMB + k0 + tx] = f2bf(tile[tx][ty + j]);
}

// ---------------- f32 -> bf16 bulk convert (key|value) ----------------
__global__ void txl_cvt2(const float* __restrict__ k, const float* __restrict__ v,
                         unsigned short* __restrict__ ko, unsigned short* __restrict__ vo){
  for (size_t c = (size_t)blockIdx.x * 256 + threadIdx.x; c < 2097152; c += (size_t)2048 * 256){
    const float* src; unsigned short* dst; size_t off;
    if (c < 1048576){ src = k; dst = ko; off = c; }
    else            { src = v; dst = vo; off = c - 1048576; }
    f32x4 a = *(const f32x4*)(src + off * 8);
    f32x4 b = *(const f32x4*)(src + off * 8 + 4);
    bf16x8 r;
    #pragma unroll
    for (int u = 0; u < 4; ++u){ r[u] = (short)f2bf(a[u]); r[u + 4] = (short)f2bf(b[u]); }
    *(bf16x8*)(dst + off * 8) = r;
  }
}

// ---------------- GEMM: C[M][1024] = A[M][1024] @ Wt^T (+bias) ----------------
// Wt is bf16 [n][k]. A is bf16 (MODE 1,2,4 via global_load_lds) or f32 (MODE 0,3).
// MODE: 0=Q (writes Qu AND Qv, scaled), 1=K, 2=V(transposed), 3=R, 4=O(f32 out)
template<int MODE>
__global__ __launch_bounds__(256)
void txl_gemm(const void* __restrict__ Ag, const unsigned short* __restrict__ Wt,
              const float* __restrict__ bias, const float* __restrict__ Ub,
              const float* __restrict__ Vb, void* __restrict__ out0,
              void* __restrict__ out1){
  const int tid = threadIdx.x;
  const int lane = tid & 63, wave = tid >> 6;
  const int lr = lane & 15, lg = lane >> 4;
  const int wm = wave >> 1, wn = wave & 1;
  const int m0 = blockIdx.y * 128, n0 = blockIdx.x * 128;
  __shared__ unsigned short At[128 * 64];
  __shared__ unsigned short Bt[128 * 64];
  f32x4 acc[4][4] = {};

  for (int kt = 0; kt < EMB / 64; ++kt){
    const int k0 = kt * 64;
    __syncthreads();
    // ---- stage A tile [128][64] ----
    if constexpr (MODE == 1 || MODE == 2 || MODE == 4){
      const unsigned short* A = (const unsigned short*)Ag;
      #pragma unroll
      for (int j = 0; j < 4; ++j){
        int row = j * 32 + (tid >> 3);
        int g = (tid & 7) ^ (row & 7);
        gload_lds16(A + (size_t)(m0 + row) * EMB + k0 + g * 8, &At[j * 2048 + wave * 512]);
      }
    } else {
      const float* A = (const float*)Ag;
      int row = tid >> 1, hf = tid & 1;
      const f32x4* s4 = (const f32x4*)(A + (size_t)(m0 + row) * EMB + k0 + hf * 32);
      #pragma unroll
      for (int c = 0; c < 4; ++c){
        f32x4 a = s4[c * 2], b = s4[c * 2 + 1];
        bf16x8 pk;
        #pragma unroll
        for (int u = 0; u < 4; ++u){ pk[u] = (short)f2bf(a[u]); pk[u + 4] = (short)f2bf(b[u]); }
        int g = hf * 4 + c;
        *(bf16x8*)&At[row * 64 + (g ^ (row & 7)) * 8] = pk;
      }
    }
    // ---- stage B tile [128][64] ----
    #pragma unroll
    for (int j = 0; j < 4; ++j){
      int row = j * 32 + (tid >> 3);
      int g = (tid & 7) ^ (row & 7);
      gload_lds16(Wt + (size_t)(n0 + row) * EMB + k0 + g * 8, &Bt[j * 2048 + wave * 512]);
    }
    __syncthreads();
    #pragma unroll
    for (int ks = 0; ks < 2; ++ks){
      bf16x8 af[4], bfr[4];
      #pragma unroll
      for (int mb = 0; mb < 4; ++mb){
        int row = wm * 64 + mb * 16 + lr;
        af[mb] = *(const bf16x8*)&At[row * 64 + ((lg + 4 * ks) ^ (row & 7)) * 8];
      }
      #pragma unroll
      for (int nb = 0; nb < 4; ++nb){
        int row = wn * 64 + nb * 16 + lr;
        bfr[nb] = *(const bf16x8*)&Bt[row * 64 + ((lg + 4 * ks) ^ (row & 7)) * 8];
      }
      __builtin_amdgcn_s_setprio(1);
      #pragma unroll
      for (int mb = 0; mb < 4; ++mb)
        #pragma unroll
        for (int nb = 0; nb < 4; ++nb)
          acc[mb][nb] = __builtin_amdgcn_mfma_f32_16x16x32_bf16(af[mb], bfr[nb], acc[mb][nb], 0, 0, 0);
      __builtin_amdgcn_s_setprio(0);
    }
  }
  #pragma unroll
  for (int mb = 0; mb < 4; ++mb){
    #pragma unroll
    for (int nb = 0; nb < 4; ++nb){
      #pragma unroll
      for (int i = 0; i < 4; ++i){
        int m = m0 + wm * 64 + mb * 16 + 4 * lg + i;
        int n = n0 + wn * 64 + nb * 16 + lr;
        float v = acc[mb][nb][i];
        if constexpr (MODE == 0){
          int q = m >> 2, b = m & 3, h = n >> 6, d = n & 63;
          size_t idx = ((((size_t)b * NH + h) * QLEN) + q) * HD + d;
          ((unsigned short*)out0)[idx] = f2bf((v + bias[n] + Ub[n]) * SLOG2E);
          ((unsigned short*)out1)[idx] = f2bf((v + bias[n] + Vb[n]) * SLOG2E);
        } else if constexpr (MODE == 1){
          int kp = m >> 2, b = m & 3, h = n >> 6, d = n & 63;
          ((unsigned short*)out0)[((((size_t)b * NH + h) * KLEN) + kp) * HD + d] = f2bf(v + bias[n]);
        } else if constexpr (MODE == 2){
          int kp = m >> 2, b = m & 3, h = n >> 6, d = n & 63;
          ((unsigned short*)out0)[((((size_t)b * NH + h) * HD) + d) * KLEN + kp] = f2bf(v + bias[n]);
        } else if constexpr (MODE == 3){
          int h = n >> 6, d = n & 63;
          ((unsigned short*)out0)[((size_t)h * KLEN + m) * HD + d] = f2bf(v);
        } else {
          ((float*)out0)[(size_t)m * EMB + n] = v + bias[n];
        }
      }
    }
  }
}

// ---------------- fused attention: barrier-free, LDS-free operands ----------------
// 2048 blocks (XCD-swizzled): (b,h) x qt(8) x quarter(4). 4 INDEPENDENT waves x 32q.
// All K/V/R MFMA fragments loaded directly global->reg (L1/L2-served). LDS only
// holds the per-wave P round-trip (2KB/wave). No __syncthreads in the k-loop.
// Fixed-max exp2 softmax => partials linear; quarters combine via atomicAdd.
__global__ __launch_bounds__(256, 3)
void txl_attn(const unsigned short* __restrict__ Qu, const unsigned short* __restrict__ Qv,
              const unsigned short* __restrict__ Kb, const unsigned short* __restrict__ Vt,
              const unsigned short* __restrict__ Rb, float* __restrict__ Opart,
              float* __restrict__ lspart){
  const int tid = threadIdx.x, lane = tid & 63, wave = tid >> 6;
  const int lr = lane & 15, lg = lane >> 4;
  const int wg = (blockIdx.x & 7) * 256 + (blockIdx.x >> 3);   // 256 blocks per XCD
  const int hb = wg >> 5;
  const int qt = (wg >> 2) & 7, qtr = wg & 3;
  const int h = hb & 15, b = hb >> 4;
  const int q0 = qt * 128;
  const int qw = q0 + 32 * wave;               // this wave's 32-row base

  __shared__ unsigned short sm_p[4][16 * 64];  // 8 KB total

  const unsigned short* quB = Qu + (((size_t)b * NH + h) * QLEN) * HD;
  const unsigned short* qvB = Qv + (((size_t)b * NH + h) * QLEN) * HD;
  const unsigned short* kB  = Kb + (((size_t)b * NH + h) * KLEN) * HD;
  const unsigned short* vB  = Vt + (((size_t)b * NH + h) * HD) * KLEN;
  const unsigned short* rB  = Rb + ((size_t)h * KLEN) * HD;

  const int nk0 = 2 * qt + 18;
  const int nk = nk0 < 32 ? nk0 : 32;
  const int kc0 = (qtr * nk) >> 2;
  const int kc1 = ((qtr + 1) * nk) >> 2;

  // Q fragments: direct global->reg, resident for the whole kernel
  bf16x8 qfu[2][2], qfv[2][2];
  #pragma unroll
  for (int j = 0; j < 2; ++j){
    int qrow = qw + 16 * j + lr;
    #pragma unroll
    for (int ks = 0; ks < 2; ++ks){
      qfu[j][ks] = *(const bf16x8*)(quB + (size_t)qrow * HD + (lg + 4 * ks) * 8);
      qfv[j][ks] = *(const bf16x8*)(qvB + (size_t)qrow * HD + (lg + 4 * ks) * 8);
    }
  }

  f32x4 o[2][4] = {};
  float ls[2][4] = {{0.f,0.f,0.f,0.f},{0.f,0.f,0.f,0.f}};

  for (int kt = kc0; kt < kc1; ++kt){
    const int k0 = kt * 64;
    const int rb0 = k0 + 896 - q0;             // band origin (>= 0; high reads masked)
    #pragma unroll
    for (int j = 0; j < 2; ++j){
      const int bbj = 7 - 2 * wave - j;        // this subtile's first band block
      const int rbase = rb0 + bbj * 16 + lr;
      f32x4 sc[4] = {};
      f32x4 tq[5] = {};
      __builtin_amdgcn_s_setprio(1);
      #pragma unroll
      for (int ks = 0; ks < 2; ++ks){
        const int dcol = (lg + 4 * ks) * 8;
        #pragma unroll
        for (int nb = 0; nb < 4; ++nb){
          bf16x8 kf = *(const bf16x8*)(kB + (size_t)(k0 + nb * 16 + lr) * HD + dcol);
          sc[nb] = __builtin_amdgcn_mfma_f32_16x16x32_bf16(qfu[j][ks], kf, sc[nb], 0, 0, 0);
        }
        #pragma unroll
        for (int x = 0; x < 5; ++x){
          bf16x8 rf = *(const bf16x8*)(rB + (size_t)(rbase + x * 16) * HD + dcol);
          tq[x] = __builtin_amdgcn_mfma_f32_16x16x32_bf16(qfv[j][ks], rf, tq[x], 0, 0, 0);
        }
      }
      __builtin_amdgcn_s_setprio(0);

      // diagonal select + mask + exp2 (fixed-max), deferred row-sum, write P
      const int qbase = qw + 16 * j;
      const bool mk = (k0 + 63 > qbase + PREVL);
      #pragma unroll
      for (int i = 0; i < 4; ++i){
        int qq = 4 * lg + i;
        int t = lr + 15 - qq;
        int srcl = (lane & 48) | (t & 15);
        int hi = t >> 4;
        float wv[5];
        #pragma unroll
        for (int x = 0; x < 5; ++x) wv[x] = __shfl(tq[x][i], srcl, 64);
        float rs = 0.f;
        #pragma unroll
        for (int nb = 0; nb < 4; ++nb){
          float s = sc[nb][i] + (hi ? wv[nb + 1] : wv[nb]);
          if (mk && (k0 + nb * 16 + lr > qbase + qq + PREVL)) s = -1e30f;
          float p = exp2f(s);
          rs += p;
          int kk = nb * 16 + lr;
          sm_p[wave][qq * 64 + (((kk >> 3) ^ (qq & 7)) << 3) + (kk & 7)] = f2bf(p);
        }
        ls[j][i] += rs;
      }

      // PV: O[16q][64d] += P @ V (V fragments direct global->reg)
      __builtin_amdgcn_s_setprio(1);
      #pragma unroll
      for (int ks = 0; ks < 2; ++ks){
        const int dcol = (lg + 4 * ks) * 8;
        bf16x8 pa = *(const bf16x8*)&sm_p[wave][lr * 64 + ((lg + 4 * ks) ^ (lr & 7)) * 8];
        #pragma unroll
        for (int db = 0; db < 4; ++db){
          bf16x8 vf = *(const bf16x8*)(vB + (size_t)(db * 16 + lr) * KLEN + k0 + dcol);
          o[j][db] = __builtin_amdgcn_mfma_f32_16x16x32_bf16(pa, vf, o[j][db], 0, 0, 0);
        }
      }
      __builtin_amdgcn_s_setprio(0);
    }
  }

  // partial accumulation (4 commutative f32 adds per element across quarters)
  const int slot = hb * 8 + qt;
  float* Ob = Opart + (size_t)slot * 8192;
  #pragma unroll
  for (int j = 0; j < 2; ++j){
    #pragma unroll
    for (int i = 0; i < 4; ++i){
      float s = ls[j][i];
      s += __shfl_xor(s, 1); s += __shfl_xor(s, 2);
      s += __shfl_xor(s, 4); s += __shfl_xor(s, 8);
      int qrel = 32 * wave + 16 * j + 4 * lg + i;
      if (lr == 0) atomicAdd(&lspart[slot * 128 + qrel], s);
      #pragma unroll
      for (int db = 0; db < 4; ++db)
        atomicAdd(&Ob[qrel * 64 + db * 16 + lr], o[j][db][i]);
    }
  }
}

// ---------------- normalize summed partials -> alpha bf16 ----------------
__global__ __launch_bounds__(256)
void txl_reduce(const float* __restrict__ Opart, const float* __restrict__ lspart,
                unsigned short* __restrict__ alpha){
  const int rb = blockIdx.x;                   // 512 = hb*8 + qt
  const int qt = rb & 7, hb = rb >> 3;
  const int h = hb & 15, b = hb >> 4;
  const f32x4* O = (const f32x4*)(Opart + (size_t)rb * 8192);
  const float* l = lspart + rb * 128;
  const int q0 = qt * 128;
  #pragma unroll
  for (int u = 0; u < 8; ++u){
    int e4 = u * 256 + threadIdx.x;
    int q = e4 >> 4, d0 = (e4 & 15) * 4;
    f32x4 ov = O[e4];
    float inv = 1.0f / l[q];
    bf16x4 r;
    #pragma unroll
    for (int e = 0; e < 4; ++e) r[e] = (short)f2bf(ov[e] * inv);
    *(bf16x4*)(alpha + ((size_t)(q0 + q) * BSZ + b) * EMB + (h << 6) + d0) = r;
  }
}

extern "C" void kernel_launch(void* const* d_in, const int* in_sizes, int n_in,
                              void* d_out, int out_size, void* d_ws, size_t ws_size,
                              hipStream_t stream) {
  const float* query = (const float*)d_in[0];
  const float* key   = (const float*)d_in[1];
  const float* value = (const float*)d_in[2];
  const float* pos   = (const float*)d_in[3];
  const float* U     = (const float*)d_in[4];
  const float* V     = (const float*)d_in[5];
  const float* Wq    = (const float*)d_in[6];
  const float* bq    = (const float*)d_in[7];
  const float* Wk    = (const float*)d_in[8];
  const float* bk    = (const float*)d_in[9];
  const float* Wv    = (const float*)d_in[10];
  const float* bv    = (const float*)d_in[11];
  const float* Wp    = (const float*)d_in[12];
  const float* Wo    = (const float*)d_in[13];
  const float* bo    = (const float*)d_in[14];

  char* w = (char*)d_ws;
  const size_t MB = 1u << 20;
  unsigned short* WqT = (unsigned short*)(w + 0 * MB);
  unsigned short* WkT = (unsigned short*)(w + 2 * MB);
  unsigned short* WvT = (unsigned short*)(w + 4 * MB);
  unsigned short* WpT = (unsigned short*)(w + 6 * MB);
  unsigned short* WoT = (unsigned short*)(w + 8 * MB);
  unsigned short* Qu  = (unsigned short*)(w + 10 * MB);
  unsigned short* Qv  = (unsigned short*)(w + 18 * MB);
  unsigned short* Kb  = (unsigned short*)(w + 26 * MB);
  unsigned short* Vt  = (unsigned short*)(w + 42 * MB);
  unsigned short* Rb  = (unsigned short*)(w + 58 * MB);
  unsigned short* kbf = (unsigned short*)(w + 62 * MB);   // 16 MB staging (dead after GEMM1)
  unsigned short* vbf = (unsigned short*)(w + 78 * MB);   // 16 MB staging (dead after GEMM2)
  float*          Opart  = (float*)(w + 62 * MB);         // 16 MB, overlays kbf
  unsigned short* alpha  = (unsigned short*)(w + 78 * MB);// 8 MB, overlays vbf
  float*          lspart = (float*)(w + 94 * MB);         // 256 KB

  txl_transpose5<<<dim3(32, 32, 5), dim3(32, 8), 0, stream>>>(Wq, Wk, Wv, Wp, Wo,
                                                              WqT, WkT, WvT, WpT, WoT);
  txl_cvt2<<<dim3(2048), 256, 0, stream>>>(key, value, kbf, vbf);

  txl_gemm<3><<<dim3(8, 16), 256, 0, stream>>>((const void*)pos,   WpT, nullptr, nullptr, nullptr, (void*)Rb, nullptr);
  txl_gemm<0><<<dim3(8, 32), 256, 0, stream>>>((const void*)query, WqT, bq, U, V, (void*)Qu, (void*)Qv);
  txl_gemm<1><<<dim3(8, 64), 256, 0, stream>>>((const void*)kbf,   WkT, bk, nullptr, nullptr, (void*)Kb, nullptr);
  txl_gemm<2><<<dim3(8, 64), 256, 0, stream>>>((const void*)vbf,   WvT, bv, nullptr, nullptr, (void*)Vt, nullptr);

  // zero partial buffers (after kbf is consumed; stream-ordered)
  hipMemsetAsync(w + 62 * MB, 0, 16 * MB, stream);
  hipMemsetAsync(w + 94 * MB, 0, 256 * 1024, stream);

  txl_attn<<<dim3(2048), 256, 0, stream>>>(Qu, Qv, Kb, Vt, Rb, Opart, lspart);
  txl_reduce<<<dim3(512), 256, 0, stream>>>(Opart, lspart, alpha);

  txl_gemm<4><<<dim3(8, 32), 256, 0, stream>>>((const void*)alpha, WoT, bo, nullptr, nullptr, d_out, nullptr);
}

// Round 8
// 428.168 us; speedup vs baseline: 1.6470x; 1.6470x over previous
//
#include <hip/hip_runtime.h>
#include <stdint.h>

#define QLEN 1024
#define KLEN 2048
#define BSZ  4
#define NH   16
#define HD   64
#define EMB  1024
#define PREVL 1024
#define SLOG2E 0.045084220027780106f   // (1/32) * log2(e): fold softmax scale + exp2 conversion

typedef __attribute__((ext_vector_type(4))) float f32x4;
typedef __attribute__((ext_vector_type(8))) short bf16x8;
typedef __attribute__((ext_vector_type(4))) short bf16x4;

__device__ __forceinline__ unsigned short f2bf(float f){
  unsigned u = __float_as_uint(f);
  u += 0x7fffu + ((u >> 16) & 1u);
  return (unsigned short)(u >> 16);
}
__device__ __forceinline__ float bf2f(unsigned short s){
  return __uint_as_float(((unsigned)s) << 16);
}

__device__ __forceinline__ void gload_lds16(const void* g, void* l){
  __builtin_amdgcn_global_load_lds((const __attribute__((address_space(1))) void*)g,
                                   (__attribute__((address_space(3))) void*)l, 16, 0, 0);
}

// ---------------- fused 5x W transpose: f32 [k][n] -> bf16 [n][k] ----------------
__global__ void txl_transpose5(const float* __restrict__ w0, const float* __restrict__ w1,
                               const float* __restrict__ w2, const float* __restrict__ w3,
                               const float* __restrict__ w4,
                               unsigned short* __restrict__ o0, unsigned short* __restrict__ o1,
                               unsigned short* __restrict__ o2, unsigned short* __restrict__ o3,
                               unsigned short* __restrict__ o4){
  const float* in; unsigned short* out;
  switch (blockIdx.z){
    case 0: in = w0; out = o0; break;
    case 1: in = w1; out = o1; break;
    case 2: in = w2; out = o2; break;
    case 3: in = w3; out = o3; break;
    default: in = w4; out = o4; break;
  }
  __shared__ float tile[32][33];
  int tx = threadIdx.x, ty = threadIdx.y;
  int k0 = blockIdx.y * 32, n0 = blockIdx.x * 32;
  #pragma unroll
  for (int j = 0; j < 32; j += 8)
    tile[ty + j][tx] = in[(size_t)(k0 + ty + j) * EMB + n0 + tx];
  __syncthreads();
  #pragma unroll
  for (int j = 0; j < 32; j += 8)
    out[(size_t)(n0 + ty + j) * EMB + k0 + tx] = f2bf(tile[tx][ty + j]);
}

// ---------------- f32 -> bf16 bulk convert (query|key|value|pos) ----------------
__global__ void txl_cvt(const float* __restrict__ q, const float* __restrict__ k,
                        const float* __restrict__ v, const float* __restrict__ p,
                        unsigned short* __restrict__ qo, unsigned short* __restrict__ ko,
                        unsigned short* __restrict__ vo, unsigned short* __restrict__ po){
  for (size_t c = (size_t)blockIdx.x * 256 + threadIdx.x; c < 2883584; c += (size_t)2048 * 256){
    const float* src; unsigned short* dst; size_t off;
    if (c < 524288)      { src = q; dst = qo; off = c; }
    else if (c < 1572864){ src = k; dst = ko; off = c - 524288; }
    else if (c < 2621440){ src = v; dst = vo; off = c - 1572864; }
    else                 { src = p; dst = po; off = c - 2621440; }
    f32x4 a = *(const f32x4*)(src + off * 8);
    f32x4 b = *(const f32x4*)(src + off * 8 + 4);
    bf16x8 r;
    #pragma unroll
    for (int u = 0; u < 4; ++u){ r[u] = (short)f2bf(a[u]); r[u + 4] = (short)f2bf(b[u]); }
    *(bf16x8*)(dst + off * 8) = r;
  }
}

// ---------------- cg[h][r] = SLOG2E * sum_d (U-V)[h,d] * R'[h,r,d] ----------------
__global__ void txl_cuv(const unsigned short* __restrict__ Rb, const float* __restrict__ U,
                        const float* __restrict__ V, float* __restrict__ cg){
  int idx = blockIdx.x * 256 + threadIdx.x;      // 16*2048
  int h = idx >> 11, r = idx & 2047;
  const bf16x8* rp = (const bf16x8*)(Rb + ((size_t)h * KLEN + r) * HD);
  float s = 0.f;
  #pragma unroll
  for (int c8 = 0; c8 < 8; ++c8){
    bf16x8 v8 = rp[c8];
    #pragma unroll
    for (int u = 0; u < 8; ++u){
      int d = c8 * 8 + u;
      s += (U[(h << 6) + d] - V[(h << 6) + d]) * bf2f((unsigned short)v8[u]);
    }
  }
  cg[idx] = s * SLOG2E;
}

// ---------------- GEMM: C[M][1024] = A[M][1024] @ Wt^T (+bias) ----------------
// A is bf16 [M][1024]; Wt is bf16 [n][k].
// MODE: 0=Q (scaled by SLOG2E, +U), 1=K, 2=V(transposed out), 3=R, 4=O(f32 out)
template<int MODE>
__global__ __launch_bounds__(256)
void txl_gemm(const unsigned short* __restrict__ Ag, const unsigned short* __restrict__ Wt,
              const float* __restrict__ bias, const float* __restrict__ Ub,
              void* __restrict__ out0){
  const int tid = threadIdx.x;
  const int lane = tid & 63, wave = tid >> 6;
  const int lr = lane & 15, lg = lane >> 4;
  const int wm = wave >> 1, wn = wave & 1;
  const int m0 = blockIdx.y * 128, n0 = blockIdx.x * 128;
  __shared__ unsigned short At[128 * 64];
  __shared__ unsigned short Bt[128 * 64];
  f32x4 acc[4][4] = {};

  for (int kt = 0; kt < EMB / 64; ++kt){
    const int k0 = kt * 64;
    __syncthreads();
    #pragma unroll
    for (int j = 0; j < 4; ++j){
      int row = j * 32 + (tid >> 3);
      int g = (tid & 7) ^ (row & 7);
      gload_lds16(Ag + (size_t)(m0 + row) * EMB + k0 + g * 8, &At[j * 2048 + wave * 512]);
      gload_lds16(Wt + (size_t)(n0 + row) * EMB + k0 + g * 8, &Bt[j * 2048 + wave * 512]);
    }
    __syncthreads();
    #pragma unroll
    for (int ks = 0; ks < 2; ++ks){
      bf16x8 af[4], bfr[4];
      #pragma unroll
      for (int mb = 0; mb < 4; ++mb){
        int row = wm * 64 + mb * 16 + lr;
        af[mb] = *(const bf16x8*)&At[row * 64 + ((lg + 4 * ks) ^ (row & 7)) * 8];
      }
      #pragma unroll
      for (int nb = 0; nb < 4; ++nb){
        int row = wn * 64 + nb * 16 + lr;
        bfr[nb] = *(const bf16x8*)&Bt[row * 64 + ((lg + 4 * ks) ^ (row & 7)) * 8];
      }
      __builtin_amdgcn_s_setprio(1);
      #pragma unroll
      for (int mb = 0; mb < 4; ++mb)
        #pragma unroll
        for (int nb = 0; nb < 4; ++nb)
          acc[mb][nb] = __builtin_amdgcn_mfma_f32_16x16x32_bf16(af[mb], bfr[nb], acc[mb][nb], 0, 0, 0);
      __builtin_amdgcn_s_setprio(0);
    }
  }
  #pragma unroll
  for (int mb = 0; mb < 4; ++mb){
    #pragma unroll
    for (int nb = 0; nb < 4; ++nb){
      #pragma unroll
      for (int i = 0; i < 4; ++i){
        int m = m0 + wm * 64 + mb * 16 + 4 * lg + i;
        int n = n0 + wn * 64 + nb * 16 + lr;
        float v = acc[mb][nb][i];
        if constexpr (MODE == 0){
          int q = m >> 2, b = m & 3, h = n >> 6, d = n & 63;
          size_t idx = ((((size_t)b * NH + h) * QLEN) + q) * HD + d;
          ((unsigned short*)out0)[idx] = f2bf((v + bias[n] + Ub[n]) * SLOG2E);
        } else if constexpr (MODE == 1){
          int kp = m >> 2, b = m & 3, h = n >> 6, d = n & 63;
          ((unsigned short*)out0)[((((size_t)b * NH + h) * KLEN) + kp) * HD + d] = f2bf(v + bias[n]);
        } else if constexpr (MODE == 2){
          int kp = m >> 2, b = m & 3, h = n >> 6, d = n & 63;
          ((unsigned short*)out0)[((((size_t)b * NH + h) * HD) + d) * KLEN + kp] = f2bf(v + bias[n]);
        } else if constexpr (MODE == 3){
          int h = n >> 6, d = n & 63;
          ((unsigned short*)out0)[((size_t)h * KLEN + m) * HD + d] = f2bf(v);
        } else {
          ((float*)out0)[(size_t)m * EMB + n] = v + bias[n];
        }
      }
    }
  }
}

// ---------------- fused attention: 64q blocks, high occupancy ----------------
// 2048 blocks (XCD-swizzled): (b,h) x qt(16) x half(2). 4 waves x 16 q-rows.
// K/V staged via global_load_lds (coalesced, read-once). R + cg fragments read
// DIRECTLY global->reg (1x amplification per wave; h-local per XCD => L2-hot).
// LDS 24KB + <=128 VGPR => 4 blocks/CU (16 waves). Plain-store partials.
__global__ __launch_bounds__(256, 4)
void txl_attn(const unsigned short* __restrict__ Qu, const unsigned short* __restrict__ Kb,
              const unsigned short* __restrict__ Vt, const unsigned short* __restrict__ Rb,
              const float* __restrict__ cg, float* __restrict__ Opart,
              float* __restrict__ lspart){
  const int tid = threadIdx.x, lane = tid & 63, wave = tid >> 6;
  const int lr = lane & 15, lg = lane >> 4;
  const int wg = (blockIdx.x & 7) * 256 + (blockIdx.x >> 3);   // 8 hb (2MB R set) per XCD
  const int hb = wg >> 5;
  const int qt = (wg >> 1) & 15, half = wg & 1;
  const int h = hb & 15, b = hb >> 4;
  const int q0 = qt * 64;
  const int qw = q0 + 16 * wave;               // this wave's 16-row base

  __shared__ union { unsigned short q[64 * 64]; unsigned short p[4][16 * 64]; } sm_u;
  __shared__ unsigned short sm_k[64 * 64];     // 8 KB
  __shared__ unsigned short sm_v[64 * 64];     // 8 KB

  const unsigned short* quB = Qu + (((size_t)b * NH + h) * QLEN) * HD;
  const unsigned short* kB  = Kb + (((size_t)b * NH + h) * KLEN) * HD;
  const unsigned short* vB  = Vt + (((size_t)b * NH + h) * HD) * KLEN;
  const unsigned short* rB  = Rb + ((size_t)h * KLEN) * HD;
  const float* cB = cg + ((size_t)h << 11);

  const int nk0 = qt + 17;
  const int nk = nk0 < 32 ? nk0 : 32;
  const int kc0 = (half * nk) >> 1;
  const int kc1 = ((half + 1) * nk) >> 1;

  // stage Q tile, hoist this wave's fragments (p-slice == own q rows: no hazard)
  #pragma unroll
  for (int j = 0; j < 2; ++j){
    int row = j * 32 + (tid >> 3);
    int g = (tid & 7) ^ (row & 7);
    gload_lds16(quB + (size_t)(q0 + row) * HD + g * 8, &sm_u.q[j * 2048 + wave * 512]);
  }
  __syncthreads();
  bf16x8 qf[2];
  {
    int row = 16 * wave + lr;
    #pragma unroll
    for (int ks = 0; ks < 2; ++ks)
      qf[ks] = *(const bf16x8*)&sm_u.q[row * 64 + ((lg + 4 * ks) ^ (row & 7)) * 8];
  }

  f32x4 o[4] = {};
  float ls[4] = {0.f, 0.f, 0.f, 0.f};

  for (int kt = kc0; kt < kc1; ++kt){
    const int k0 = kt * 64;
    const int rbase0 = k0 + 1008 - q0 - 16 * wave;   // wave band origin (>= 0)
    __syncthreads();                                  // prev PV done reading sm_k/sm_v
    #pragma unroll
    for (int j = 0; j < 2; ++j){
      int row = j * 32 + (tid >> 3);
      int g = (tid & 7) ^ (row & 7);
      gload_lds16(kB + (size_t)(k0 + row) * HD + g * 8, &sm_k[j * 2048 + wave * 512]);
      gload_lds16(vB + (size_t)row * KLEN + k0 + g * 8, &sm_v[j * 2048 + wave * 512]);
    }
    // cg band fragments: direct global (issue early, used after MFMAs)
    float cgl[5];
    #pragma unroll
    for (int x = 0; x < 5; ++x){
      int rc = rbase0 + x * 16 + lr; rc = rc < KLEN - 1 ? rc : KLEN - 1;
      cgl[x] = cB[rc];
    }
    __syncthreads();                                  // K/V staged

    // content (LDS K) + position band (direct-global R)
    f32x4 sc[4] = {};
    f32x4 tq[5] = {};
    __builtin_amdgcn_s_setprio(1);
    #pragma unroll
    for (int ks = 0; ks < 2; ++ks){
      const int dcol = (lg + 4 * ks) * 8;
      #pragma unroll
      for (int nb = 0; nb < 4; ++nb){
        int row = nb * 16 + lr;
        bf16x8 kf = *(const bf16x8*)&sm_k[row * 64 + ((lg + 4 * ks) ^ (row & 7)) * 8];
        sc[nb] = __builtin_amdgcn_mfma_f32_16x16x32_bf16(qf[ks], kf, sc[nb], 0, 0, 0);
      }
      #pragma unroll
      for (int x = 0; x < 5; ++x){
        int rc = rbase0 + x * 16 + lr; rc = rc < KLEN - 1 ? rc : KLEN - 1;
        bf16x8 rf = *(const bf16x8*)(rB + (size_t)rc * HD + dcol);
        tq[x] = __builtin_amdgcn_mfma_f32_16x16x32_bf16(qf[ks], rf, tq[x], 0, 0, 0);
      }
    }
    __builtin_amdgcn_s_setprio(0);

    // cg pre-subtract (per band column; column = lr, same for all 4 C-rows)
    #pragma unroll
    for (int x = 0; x < 5; ++x)
      #pragma unroll
      for (int e = 0; e < 4; ++e) tq[x][e] -= cgl[x];

    // diagonal select + mask + exp2 (fixed-max), deferred row-sum, write P
    const bool mk = (k0 + 63 > qw + PREVL);
    #pragma unroll
    for (int i = 0; i < 4; ++i){
      int qq = 4 * lg + i;
      int t = lr + 15 - qq;
      int srcl = (lane & 48) | (t & 15);
      int hi = t >> 4;
      float wv[5];
      #pragma unroll
      for (int x = 0; x < 5; ++x) wv[x] = __shfl(tq[x][i], srcl, 64);
      float rs = 0.f;
      #pragma unroll
      for (int nb = 0; nb < 4; ++nb){
        float s = sc[nb][i] + (hi ? wv[nb + 1] : wv[nb]);
        if (mk && (k0 + nb * 16 + lr > qw + qq + PREVL)) s = -1e30f;
        float p = exp2f(s);
        rs += p;
        int kk = nb * 16 + lr;
        sm_u.p[wave][qq * 64 + (((kk >> 3) ^ (qq & 7)) << 3) + (kk & 7)] = f2bf(p);
      }
      ls[i] += rs;
    }
    asm volatile("s_waitcnt lgkmcnt(0)" ::: "memory");

    // PV: O[16q][64d] += P @ V
    __builtin_amdgcn_s_setprio(1);
    #pragma unroll
    for (int ks = 0; ks < 2; ++ks){
      bf16x8 pa = *(const bf16x8*)&sm_u.p[wave][lr * 64 + ((lg + 4 * ks) ^ (lr & 7)) * 8];
      #pragma unroll
      for (int db = 0; db < 4; ++db){
        int row = db * 16 + lr;
        bf16x8 vf = *(const bf16x8*)&sm_v[row * 64 + ((lg + 4 * ks) ^ (row & 7)) * 8];
        o[db] = __builtin_amdgcn_mfma_f32_16x16x32_bf16(pa, vf, o[db], 0, 0, 0);
      }
    }
    __builtin_amdgcn_s_setprio(0);
  }

  // write partials (plain stores; halves disjoint)
  float* Ob = Opart + (size_t)wg * 4096;
  #pragma unroll
  for (int i = 0; i < 4; ++i){
    float s = ls[i];
    s += __shfl_xor(s, 1); s += __shfl_xor(s, 2);
    s += __shfl_xor(s, 4); s += __shfl_xor(s, 8);
    int qrel = 16 * wave + 4 * lg + i;
    if (lr == 0) lspart[wg * 64 + qrel] = s;
    #pragma unroll
    for (int db = 0; db < 4; ++db)
      Ob[qrel * 64 + db * 16 + lr] = o[db][i];
  }
}

// ---------------- combine 2 half-partials + normalize -> alpha bf16 ----------------
__global__ __launch_bounds__(256)
void txl_reduce(const float* __restrict__ Opart, const float* __restrict__ lspart,
                unsigned short* __restrict__ alpha){
  const int rb = blockIdx.x;                   // 1024 = hb*16 + qt
  const int qt = rb & 15, hb = rb >> 4;
  const int h = hb & 15, b = hb >> 4;
  const int wg0 = hb * 32 + qt * 2;
  const f32x4* O0 = (const f32x4*)(Opart + (size_t)wg0 * 4096);
  const f32x4* O1 = O0 + 1024;
  const float* l0 = lspart + wg0 * 64;
  const float* l1 = l0 + 64;
  const int q0 = qt * 64;
  #pragma unroll
  for (int u = 0; u < 4; ++u){
    int e4 = u * 256 + threadIdx.x;
    int q = e4 >> 4, d0 = (e4 & 15) * 4;
    f32x4 ov = O0[e4] + O1[e4];
    float inv = 1.0f / (l0[q] + l1[q]);
    bf16x4 r;
    #pragma unroll
    for (int e = 0; e < 4; ++e) r[e] = (short)f2bf(ov[e] * inv);
    *(bf16x4*)(alpha + ((size_t)(q0 + q) * BSZ + b) * EMB + (h << 6) + d0) = r;
  }
}

extern "C" void kernel_launch(void* const* d_in, const int* in_sizes, int n_in,
                              void* d_out, int out_size, void* d_ws, size_t ws_size,
                              hipStream_t stream) {
  const float* query = (const float*)d_in[0];
  const float* key   = (const float*)d_in[1];
  const float* value = (const float*)d_in[2];
  const float* pos   = (const float*)d_in[3];
  const float* U     = (const float*)d_in[4];
  const float* V     = (const float*)d_in[5];
  const float* Wq    = (const float*)d_in[6];
  const float* bq    = (const float*)d_in[7];
  const float* Wk    = (const float*)d_in[8];
  const float* bk    = (const float*)d_in[9];
  const float* Wv    = (const float*)d_in[10];
  const float* bv    = (const float*)d_in[11];
  const float* Wp    = (const float*)d_in[12];
  const float* Wo    = (const float*)d_in[13];
  const float* bo    = (const float*)d_in[14];

  char* w = (char*)d_ws;
  const size_t MB = 1u << 20;
  unsigned short* WqT = (unsigned short*)(w + 0 * MB);
  unsigned short* WkT = (unsigned short*)(w + 2 * MB);
  unsigned short* WvT = (unsigned short*)(w + 4 * MB);
  unsigned short* WpT = (unsigned short*)(w + 6 * MB);
  unsigned short* WoT = (unsigned short*)(w + 8 * MB);
  unsigned short* Qu  = (unsigned short*)(w + 10 * MB);
  unsigned short* Kb  = (unsigned short*)(w + 18 * MB);
  unsigned short* Vt  = (unsigned short*)(w + 34 * MB);
  unsigned short* Rb  = (unsigned short*)(w + 50 * MB);
  float*          cgp = (float*)(w + 54 * MB);
  unsigned short* qbf = (unsigned short*)(w + 55 * MB);   // dead after GEMM0 -> alpha
  unsigned short* kbf = (unsigned short*)(w + 63 * MB);   // dead after GEMM1 -> Opart
  unsigned short* vbf = (unsigned short*)(w + 79 * MB);   // dead after GEMM2 -> Opart
  unsigned short* pbf = (unsigned short*)(w + 95 * MB);   // dead after GEMM3 -> lspart
  unsigned short* alpha  = qbf;
  float*          Opart  = (float*)(w + 63 * MB);         // 32 MB
  float*          lspart = (float*)(w + 95 * MB);         // 512 KB

  txl_transpose5<<<dim3(32, 32, 5), dim3(32, 8), 0, stream>>>(Wq, Wk, Wv, Wp, Wo,
                                                              WqT, WkT, WvT, WpT, WoT);
  txl_cvt<<<dim3(2048), 256, 0, stream>>>(query, key, value, pos, qbf, kbf, vbf, pbf);

  txl_gemm<3><<<dim3(8, 16), 256, 0, stream>>>(pbf, WpT, nullptr, nullptr, (void*)Rb);
  txl_gemm<0><<<dim3(8, 32), 256, 0, stream>>>(qbf, WqT, bq, U, (void*)Qu);
  txl_gemm<1><<<dim3(8, 64), 256, 0, stream>>>(kbf, WkT, bk, nullptr, (void*)Kb);
  txl_gemm<2><<<dim3(8, 64), 256, 0, stream>>>(vbf, WvT, bv, nullptr, (void*)Vt);

  txl_cuv<<<dim3(128), 256, 0, stream>>>(Rb, U, V, cgp);

  txl_attn<<<dim3(2048), 256, 0, stream>>>(Qu, Kb, Vt, Rb, cgp, Opart, lspart);
  txl_reduce<<<dim3(1024), 256, 0, stream>>>(Opart, lspart, alpha);

  txl_gemm<4><<<dim3(8, 32), 256, 0, stream>>>((const unsigned short*)alpha, WoT, bo, nullptr, d_out);
}

// Round 9
// 295.720 us; speedup vs baseline: 2.3847x; 1.4479x over previous
//
#include <hip/hip_runtime.h>
#include <stdint.h>

#define QLEN 1024
#define KLEN 2048
#define BSZ  4
#define NH   16
#define HD   64
#define EMB  1024
#define PREVL 1024
#define SLOG2E 0.045084220027780106f   // (1/32) * log2(e): fold softmax scale + exp2 conversion

typedef __attribute__((ext_vector_type(4))) float f32x4;
typedef __attribute__((ext_vector_type(8))) short bf16x8;
typedef __attribute__((ext_vector_type(4))) short bf16x4;

__device__ __forceinline__ unsigned short f2bf(float f){
  unsigned u = __float_as_uint(f);
  u += 0x7fffu + ((u >> 16) & 1u);
  return (unsigned short)(u >> 16);
}

__device__ __forceinline__ void gload_lds16(const void* g, void* l){
  __builtin_amdgcn_global_load_lds((const __attribute__((address_space(1))) void*)g,
                                   (__attribute__((address_space(3))) void*)l, 16, 0, 0);
}

// ---------------- fused 5x W transpose: f32 [k][n] -> bf16 [n][k] ----------------
__global__ void txl_transpose5(const float* __restrict__ w0, const float* __restrict__ w1,
                               const float* __restrict__ w2, const float* __restrict__ w3,
                               const float* __restrict__ w4,
                               unsigned short* __restrict__ o0, unsigned short* __restrict__ o1,
                               unsigned short* __restrict__ o2, unsigned short* __restrict__ o3,
                               unsigned short* __restrict__ o4){
  const float* in; unsigned short* out;
  switch (blockIdx.z){
    case 0: in = w0; out = o0; break;
    case 1: in = w1; out = o1; break;
    case 2: in = w2; out = o2; break;
    case 3: in = w3; out = o3; break;
    default: in = w4; out = o4; break;
  }
  __shared__ float tile[32][33];
  int tx = threadIdx.x, ty = threadIdx.y;
  int k0 = blockIdx.y * 32, n0 = blockIdx.x * 32;
  #pragma unroll
  for (int j = 0; j < 32; j += 8)
    tile[ty + j][tx] = in[(size_t)(k0 + ty + j) * EMB + n0 + tx];
  __syncthreads();
  #pragma unroll
  for (int j = 0; j < 32; j += 8)
    out[(size_t)(n0 + ty + j) * EMB + k0 + tx] = f2bf(tile[tx][ty + j]);
}

// ---------------- f32 -> bf16 bulk convert (query|key|value|pos) ----------------
__global__ void txl_cvt(const float* __restrict__ q, const float* __restrict__ k,
                        const float* __restrict__ v, const float* __restrict__ p,
                        unsigned short* __restrict__ qo, unsigned short* __restrict__ ko,
                        unsigned short* __restrict__ vo, unsigned short* __restrict__ po){
  for (size_t c = (size_t)blockIdx.x * 256 + threadIdx.x; c < 2883584; c += (size_t)2048 * 256){
    const float* src; unsigned short* dst; size_t off;
    if (c < 524288)      { src = q; dst = qo; off = c; }
    else if (c < 1572864){ src = k; dst = ko; off = c - 524288; }
    else if (c < 2621440){ src = v; dst = vo; off = c - 1572864; }
    else                 { src = p; dst = po; off = c - 2621440; }
    f32x4 a = *(const f32x4*)(src + off * 8);
    f32x4 b = *(const f32x4*)(src + off * 8 + 4);
    bf16x8 r;
    #pragma unroll
    for (int u = 0; u < 4; ++u){ r[u] = (short)f2bf(a[u]); r[u + 4] = (short)f2bf(b[u]); }
    *(bf16x8*)(dst + off * 8) = r;
  }
}

// ---------------- GEMM: C[M][1024] = A[M][1024] @ Wt^T (+bias) ----------------
// A is bf16 [M][1024]; Wt is bf16 [n][k].
// MODE: 0=Q (dual out: Qu,Qv, prescaled by SLOG2E), 1=K, 2=V(transposed), 3=R, 4=O(f32)
template<int MODE>
__global__ __launch_bounds__(256)
void txl_gemm(const unsigned short* __restrict__ Ag, const unsigned short* __restrict__ Wt,
              const float* __restrict__ bias, const float* __restrict__ Ub,
              const float* __restrict__ Vb, void* __restrict__ out0,
              void* __restrict__ out1){
  const int tid = threadIdx.x;
  const int lane = tid & 63, wave = tid >> 6;
  const int lr = lane & 15, lg = lane >> 4;
  const int wm = wave >> 1, wn = wave & 1;
  const int m0 = blockIdx.y * 128, n0 = blockIdx.x * 128;
  __shared__ unsigned short At[128 * 64];
  __shared__ unsigned short Bt[128 * 64];
  f32x4 acc[4][4] = {};

  for (int kt = 0; kt < EMB / 64; ++kt){
    const int k0 = kt * 64;
    __syncthreads();
    #pragma unroll
    for (int j = 0; j < 4; ++j){
      int row = j * 32 + (tid >> 3);
      int g = (tid & 7) ^ (row & 7);
      gload_lds16(Ag + (size_t)(m0 + row) * EMB + k0 + g * 8, &At[j * 2048 + wave * 512]);
      gload_lds16(Wt + (size_t)(n0 + row) * EMB + k0 + g * 8, &Bt[j * 2048 + wave * 512]);
    }
    __syncthreads();
    #pragma unroll
    for (int ks = 0; ks < 2; ++ks){
      bf16x8 af[4], bfr[4];
      #pragma unroll
      for (int mb = 0; mb < 4; ++mb){
        int row = wm * 64 + mb * 16 + lr;
        af[mb] = *(const bf16x8*)&At[row * 64 + ((lg + 4 * ks) ^ (row & 7)) * 8];
      }
      #pragma unroll
      for (int nb = 0; nb < 4; ++nb){
        int row = wn * 64 + nb * 16 + lr;
        bfr[nb] = *(const bf16x8*)&Bt[row * 64 + ((lg + 4 * ks) ^ (row & 7)) * 8];
      }
      __builtin_amdgcn_s_setprio(1);
      #pragma unroll
      for (int mb = 0; mb < 4; ++mb)
        #pragma unroll
        for (int nb = 0; nb < 4; ++nb)
          acc[mb][nb] = __builtin_amdgcn_mfma_f32_16x16x32_bf16(af[mb], bfr[nb], acc[mb][nb], 0, 0, 0);
      __builtin_amdgcn_s_setprio(0);
    }
  }
  #pragma unroll
  for (int mb = 0; mb < 4; ++mb){
    #pragma unroll
    for (int nb = 0; nb < 4; ++nb){
      #pragma unroll
      for (int i = 0; i < 4; ++i){
        int m = m0 + wm * 64 + mb * 16 + 4 * lg + i;
        int n = n0 + wn * 64 + nb * 16 + lr;
        float v = acc[mb][nb][i];
        if constexpr (MODE == 0){
          int q = m >> 2, b = m & 3, h = n >> 6, d = n & 63;
          size_t idx = ((((size_t)b * NH + h) * QLEN) + q) * HD + d;
          float base = v + bias[n];
          ((unsigned short*)out0)[idx] = f2bf((base + Ub[n]) * SLOG2E);
          ((unsigned short*)out1)[idx] = f2bf((base + Vb[n]) * SLOG2E);
        } else if constexpr (MODE == 1){
          int kp = m >> 2, b = m & 3, h = n >> 6, d = n & 63;
          ((unsigned short*)out0)[((((size_t)b * NH + h) * KLEN) + kp) * HD + d] = f2bf(v + bias[n]);
        } else if constexpr (MODE == 2){
          int kp = m >> 2, b = m & 3, h = n >> 6, d = n & 63;
          ((unsigned short*)out0)[((((size_t)b * NH + h) * HD) + d) * KLEN + kp] = f2bf(v + bias[n]);
        } else if constexpr (MODE == 3){
          int h = n >> 6, d = n & 63;
          ((unsigned short*)out0)[((size_t)h * KLEN + m) * HD + d] = f2bf(v);
        } else {
          ((float*)out0)[(size_t)m * EMB + n] = v + bias[n];
        }
      }
    }
  }
}

// ---------------- fused attention: exact R1 structure + fixed-max exp2 ----------------
// grid (16 qt, 16 h, 4 b), 256 threads = 4 waves x 16 q-rows. K/V/R all LDS-staged
// via global_load_lds. Diagonal select via per-wave sm_t round-trip (stride 81).
__global__ __launch_bounds__(256)
void txl_attn(const unsigned short* __restrict__ Qu, const unsigned short* __restrict__ Qv,
              const unsigned short* __restrict__ Kb, const unsigned short* __restrict__ Vt,
              const unsigned short* __restrict__ Rb, unsigned short* __restrict__ alpha){
  const int tid = threadIdx.x, lane = tid & 63, wave = tid >> 6;
  const int lr = lane & 15, lg = lane >> 4;
  const int qt = blockIdx.x, h = blockIdx.y, b = blockIdx.z;
  const int q0 = qt * 64;
  const int myq0 = q0 + 16 * wave;

  __shared__ union { unsigned short q[2][64 * 64]; unsigned short p[4][16 * 64]; } smq; // 16 KB
  __shared__ unsigned short sm_k[64 * 64];      // 8 KB
  __shared__ unsigned short sm_v[64 * 64];      // 8 KB
  __shared__ unsigned short sm_r[128 * 64];     // 16 KB
  __shared__ float sm_t[4][16 * 81];            // 20.25 KB, stride 81 kills write conflicts

  const unsigned short* quB = Qu + (((size_t)b * NH + h) * QLEN) * HD;
  const unsigned short* qvB = Qv + (((size_t)b * NH + h) * QLEN) * HD;
  const unsigned short* kB  = Kb + (((size_t)b * NH + h) * KLEN) * HD;
  const unsigned short* vB  = Vt + (((size_t)b * NH + h) * HD) * KLEN;
  const unsigned short* rB  = Rb + ((size_t)h * KLEN) * HD;

  // stage Qu/Qv tiles, then hoist this wave's fragments
  #pragma unroll
  for (int j = 0; j < 2; ++j){
    int row = j * 32 + (tid >> 3);
    int g = (tid & 7) ^ (row & 7);
    gload_lds16(quB + (size_t)(q0 + row) * HD + g * 8, &smq.q[0][j * 2048 + wave * 512]);
    gload_lds16(qvB + (size_t)(q0 + row) * HD + g * 8, &smq.q[1][j * 2048 + wave * 512]);
  }
  __syncthreads();
  bf16x8 qfu[2], qfv[2];
  {
    int row = 16 * wave + lr;
    #pragma unroll
    for (int ks = 0; ks < 2; ++ks){
      qfu[ks] = *(const bf16x8*)&smq.q[0][row * 64 + ((lg + 4 * ks) ^ (row & 7)) * 8];
      qfv[ks] = *(const bf16x8*)&smq.q[1][row * 64 + ((lg + 4 * ks) ^ (row & 7)) * 8];
    }
  }

  f32x4 o[4] = {};
  float ls[4] = {0.f, 0.f, 0.f, 0.f};

  const int nk0 = qt + 17;
  const int nk = nk0 < 32 ? nk0 : 32;
  const int roff = 48 - 16 * wave;             // this wave's R rows within the 128-row band

  for (int kt = 0; kt < nk; ++kt){
    const int k0 = kt * 64;
    const int rbase = k0 + (QLEN - 64) - q0;   // shared band origin (>= 0)
    __syncthreads();
    // stage K, V tiles
    #pragma unroll
    for (int j = 0; j < 2; ++j){
      int row = j * 32 + (tid >> 3);
      int g = (tid & 7) ^ (row & 7);
      gload_lds16(kB + (size_t)(k0 + row) * HD + g * 8, &sm_k[j * 2048 + wave * 512]);
      gload_lds16(vB + (size_t)row * KLEN + k0 + g * 8, &sm_v[j * 2048 + wave * 512]);
    }
    // stage R band (128 rows, clamped high; clamped rows feed only masked elements)
    #pragma unroll
    for (int j = 0; j < 4; ++j){
      int row = j * 32 + (tid >> 3);
      int g = (tid & 7) ^ (row & 7);
      int r = rbase + row; if (r > KLEN - 1) r = KLEN - 1;
      gload_lds16(rB + (size_t)r * HD + g * 8, &sm_r[j * 2048 + wave * 512]);
    }
    __syncthreads();

    // content scores S_c[16q][64k] and position band T[16q][80r]
    f32x4 sc[4] = {};
    f32x4 tt[5] = {};
    __builtin_amdgcn_s_setprio(1);
    #pragma unroll
    for (int ks = 0; ks < 2; ++ks){
      #pragma unroll
      for (int nb = 0; nb < 4; ++nb){
        int row = nb * 16 + lr;
        bf16x8 kf = *(const bf16x8*)&sm_k[row * 64 + ((lg + 4 * ks) ^ (row & 7)) * 8];
        sc[nb] = __builtin_amdgcn_mfma_f32_16x16x32_bf16(qfu[ks], kf, sc[nb], 0, 0, 0);
      }
      #pragma unroll
      for (int rb = 0; rb < 5; ++rb){
        int row = roff + rb * 16 + lr;
        bf16x8 rf = *(const bf16x8*)&sm_r[row * 64 + ((lg + 4 * ks) ^ (row & 7)) * 8];
        tt[rb] = __builtin_amdgcn_mfma_f32_16x16x32_bf16(qfv[ks], rf, tt[rb], 0, 0, 0);
      }
    }
    __builtin_amdgcn_s_setprio(0);

    // sm_t round-trip for the rel-shift diagonal (per-wave region; stride 81)
    float* tw = sm_t[wave];
    #pragma unroll
    for (int rb = 0; rb < 5; ++rb)
      #pragma unroll
      for (int i = 0; i < 4; ++i)
        tw[(4 * lg + i) * 81 + rb * 16 + lr] = tt[rb][i];
    asm volatile("s_waitcnt lgkmcnt(0)" ::: "memory");

    // assemble scores, mask, exp2 (fixed-max), deferred row-sum, write P
    #pragma unroll
    for (int i = 0; i < 4; ++i){
      int qq = 4 * lg + i;
      int qglob = myq0 + qq;
      float rs = 0.f;
      #pragma unroll
      for (int nb = 0; nb < 4; ++nb){
        int kk = nb * 16 + lr;
        float tv = tw[qq * 81 + kk + 15 - qq];   // diagonal: r = k + (QLEN-1) - q
        float s = sc[nb][i] + tv;
        if (k0 + kk > qglob + PREVL) s = -1e30f;
        float p = exp2f(s);
        rs += p;
        smq.p[wave][qq * 64 + (((kk >> 3) ^ (qq & 7)) << 3) + (kk & 7)] = f2bf(p);
      }
      ls[i] += rs;
    }
    asm volatile("s_waitcnt lgkmcnt(0)" ::: "memory");

    // PV: O[16q][64d] += P @ V
    __builtin_amdgcn_s_setprio(1);
    #pragma unroll
    for (int ks = 0; ks < 2; ++ks){
      bf16x8 pa = *(const bf16x8*)&smq.p[wave][lr * 64 + ((lg + 4 * ks) ^ (lr & 7)) * 8];
      #pragma unroll
      for (int db = 0; db < 4; ++db){
        int row = db * 16 + lr;
        bf16x8 vf = *(const bf16x8*)&sm_v[row * 64 + ((lg + 4 * ks) ^ (row & 7)) * 8];
        o[db] = __builtin_amdgcn_mfma_f32_16x16x32_bf16(pa, vf, o[db], 0, 0, 0);
      }
    }
    __builtin_amdgcn_s_setprio(0);
  }

  // epilogue: reduce deferred row-sums, normalize, write alpha[q][b][h*64+d]
  #pragma unroll
  for (int i = 0; i < 4; ++i){
    float s = ls[i];
    s += __shfl_xor(s, 1); s += __shfl_xor(s, 2);
    s += __shfl_xor(s, 4); s += __shfl_xor(s, 8);
    float inv = 1.0f / s;
    int q = myq0 + 4 * lg + i;
    #pragma unroll
    for (int db = 0; db < 4; ++db){
      int e = (h << 6) + db * 16 + lr;
      alpha[((size_t)q * BSZ + b) * EMB + e] = f2bf(o[db][i] * inv);
    }
  }
}

extern "C" void kernel_launch(void* const* d_in, const int* in_sizes, int n_in,
                              void* d_out, int out_size, void* d_ws, size_t ws_size,
                              hipStream_t stream) {
  const float* query = (const float*)d_in[0];
  const float* key   = (const float*)d_in[1];
  const float* value = (const float*)d_in[2];
  const float* pos   = (const float*)d_in[3];
  const float* U     = (const float*)d_in[4];
  const float* V     = (const float*)d_in[5];
  const float* Wq    = (const float*)d_in[6];
  const float* bq    = (const float*)d_in[7];
  const float* Wk    = (const float*)d_in[8];
  const float* bk    = (const float*)d_in[9];
  const float* Wv    = (const float*)d_in[10];
  const float* bv    = (const float*)d_in[11];
  const float* Wp    = (const float*)d_in[12];
  const float* Wo    = (const float*)d_in[13];
  const float* bo    = (const float*)d_in[14];

  char* w = (char*)d_ws;
  const size_t MB = 1u << 20;
  unsigned short* WqT = (unsigned short*)(w + 0 * MB);
  unsigned short* WkT = (unsigned short*)(w + 2 * MB);
  unsigned short* WvT = (unsigned short*)(w + 4 * MB);
  unsigned short* WpT = (unsigned short*)(w + 6 * MB);
  unsigned short* WoT = (unsigned short*)(w + 8 * MB);
  unsigned short* Qu  = (unsigned short*)(w + 10 * MB);
  unsigned short* Qv  = (unsigned short*)(w + 18 * MB);
  unsigned short* Kb  = (unsigned short*)(w + 26 * MB);
  unsigned short* Vt  = (unsigned short*)(w + 42 * MB);
  unsigned short* Rb  = (unsigned short*)(w + 58 * MB);
  unsigned short* qbf = (unsigned short*)(w + 62 * MB);   // dead after GEMM0 -> alpha
  unsigned short* kbf = (unsigned short*)(w + 70 * MB);
  unsigned short* vbf = (unsigned short*)(w + 86 * MB);
  unsigned short* pbf = (unsigned short*)(w + 102 * MB);
  unsigned short* alpha = qbf;

  txl_transpose5<<<dim3(32, 32, 5), dim3(32, 8), 0, stream>>>(Wq, Wk, Wv, Wp, Wo,
                                                              WqT, WkT, WvT, WpT, WoT);
  txl_cvt<<<dim3(2048), 256, 0, stream>>>(query, key, value, pos, qbf, kbf, vbf, pbf);

  txl_gemm<3><<<dim3(8, 16), 256, 0, stream>>>(pbf, WpT, nullptr, nullptr, nullptr, (void*)Rb, nullptr);
  txl_gemm<0><<<dim3(8, 32), 256, 0, stream>>>(qbf, WqT, bq, U, V, (void*)Qu, (void*)Qv);
  txl_gemm<1><<<dim3(8, 64), 256, 0, stream>>>(kbf, WkT, bk, nullptr, nullptr, (void*)Kb, nullptr);
  txl_gemm<2><<<dim3(8, 64), 256, 0, stream>>>(vbf, WvT, bv, nullptr, nullptr, (void*)Vt, nullptr);

  txl_attn<<<dim3(16, 16, 4), 256, 0, stream>>>(Qu, Qv, Kb, Vt, Rb, alpha);

  txl_gemm<4><<<dim3(8, 32), 256, 0, stream>>>(alpha, WoT, bo, nullptr, nullptr, d_out, nullptr);
}